// Round 23
// baseline (57.293 us; speedup 1.0000x reference)
//
#include <hip/hip_runtime.h>

#define F_BINS  257
#define T_STEPS 65536
#define N_ACT   256
#define TM      128           // t-columns per k_gemm block (4 waves x 32t)
#define NBLK_G  512           // T_STEPS / TM  -> 2 blocks/CU
#define NTHR    256           // 4 waves
#define XO_PB   8224          // float4 per block: 4210688/512 exact (32/thr + 32 rem)

typedef float f32x4 __attribute__((ext_vector_type(4)));
typedef short s16x8 __attribute__((ext_vector_type(8)));
typedef unsigned u32x4 __attribute__((ext_vector_type(4)));

// ws layout (all fully written every call - no memset needed):
//   [1024]   double partial[NBLK_G=512]  (per-block xo^2 sums)
//   [20480]  double corrp[257]           (per-f correction sums)
//   [24576]  unsigned maskp[NBLK_G*8]
//   [65536]  uchar Gfrag[147456]         (B frags: [kk][ng][lane][16B])
#define WS_PART  1024
#define WS_CORR  20480
#define WS_MASK  24576
#define WS_GFRAG 65536

__device__ __forceinline__ unsigned short f2bf_rne(float x) {
  unsigned u = __builtin_bit_cast(unsigned, x);
  return (unsigned short)((u + 0x7FFFu + ((u >> 16) & 1u)) >> 16);
}
// bf16(hi)<<16 | bf16(lo) by truncation: one v_perm_b32
__device__ __forceinline__ unsigned pack_bf(float hi, float lo) {
  return __builtin_amdgcn_perm(__builtin_bit_cast(unsigned, hi),
                               __builtin_bit_cast(unsigned, lo), 0x07060302u);
}

// ---------------------------------------------------------------------------
// B fragments in MFMA order:
// Gfrag[((kk*16+ng)*64+lane)*16] = 8 bf16 of G[f=32kk+8(lane>>4)+j][a=16ng+(lane&15)]
// ---------------------------------------------------------------------------
__global__ __launch_bounds__(256) void k_prep(const float* __restrict__ G,
                                              unsigned char* __restrict__ gfrag) {
  const int u = blockIdx.x * 256 + threadIdx.x;   // 0..9215
  const int lane = u & 63, ng = (u >> 6) & 15, kk = u >> 10;
  const int r16 = lane & 15, g = lane >> 4;
  const int a = ng * 16 + r16;
  unsigned short h[8];
#pragma unroll
  for (int j = 0; j < 8; ++j) {
    const int f = kk * 32 + 8 * g + j;
    h[j] = (f < F_BINS) ? f2bf_rne(G[f * N_ACT + a]) : (unsigned short)0;
  }
  u32x4 w;
#pragma unroll
  for (int i = 0; i < 4; ++i)
    w[i] = (unsigned)h[2 * i] | ((unsigned)h[2 * i + 1] << 16);
  *(u32x4*)(gfrag + (size_t)u * 16) = w;
}

// ---------------------------------------------------------------------------
// GEMM+argmax+xo^2, 2 blocks/CU (R18/R22 core). Delta vs R22: the xo
// rounds-0/1 (+remainder) prefill moves into the PROLOGUE (after STAGE_BH(0),
// before A-packing) so the xo HBM fetch runs concurrently with the xs
// stream; in-order vmcnt retirement makes the early issue safe (packing
// va[4..8] just forces xo's early retirement into registers).
// ---------------------------------------------------------------------------
__global__ __launch_bounds__(NTHR, 2) void k_gemm(
    const float* __restrict__ xs, const float4* __restrict__ xo4,
    const unsigned char* __restrict__ gfrag,
    unsigned* __restrict__ maskp, double* __restrict__ partial) {
  const int tid = threadIdx.x, lane = tid & 63, wv = tid >> 6;
  const int g = lane >> 4, r16 = lane & 15;
  const int t0 = blockIdx.x * TM;
  const int tcol = t0 + 32 * wv + 2 * r16;   // float2 load column

  __shared__ __align__(16) unsigned char Bh[73728];  // one action-half of B
  __shared__ unsigned lmask[8];
  __shared__ double sdw[4];
  if (tid < 8) lmask[tid] = 0u;

  // stage action-half hv: 72 chunks of 1KB; wave wv does idx 18wv..18wv+17
#define STAGE_BH(hv)                                                          \
  {                                                                           \
    _Pragma("unroll") for (int idx = 0; idx < 18; ++idx) {                    \
      const int j = 18 * wv + idx;         /* 0..71: dst chunk */             \
      const int kkc = j >> 3, ic = j & 7;                                     \
      const unsigned char* src = gfrag +                                      \
          (size_t)(kkc * 16 + 8 * (hv) + ic) * 1024 + (size_t)lane * 16;      \
      unsigned char* dst = &Bh[j * 1024];                                     \
      __builtin_amdgcn_global_load_lds(                                       \
          (const __attribute__((address_space(1))) unsigned*)src,             \
          (__attribute__((address_space(3))) unsigned*)dst, 16, 0, 0);        \
    }                                                                         \
  }
  // A batch: 8 float2 loads (f-rows 32kkv+8g..+8g+7 at fixed 2 t's)
#define LOADB(slot, kkv)                                                      \
  {                                                                           \
    _Pragma("unroll") for (int j = 0; j < 8; ++j) {                           \
      int f = 32 * (kkv) + 8 * g + j;                                         \
      if ((kkv) == 8) f = f > 256 ? 256 : f; /* Gfrag zero rows cover pad */  \
      va[slot][j] = *(const float2*)(xs + (size_t)f * T_STEPS + tcol);        \
    }                                                                         \
  }

  float2 va[4][8];
  LOADB(0, 0) LOADB(1, 1) LOADB(2, 2) LOADB(3, 3)
  __builtin_amdgcn_sched_barrier(0);
  STAGE_BH(0)                      // after A batches 0-3, before 4-8
  __builtin_amdgcn_sched_barrier(0);

  // ---- xo prefill rounds 0,1 + remainder: issued HERE so the xo fetch
  //      overlaps the xs prologue stream (consumed after the argmax) ----
  const float4* xop = xo4 + (size_t)blockIdx.x * XO_PB + tid;
  float4 xv[2][8];
#pragma unroll
  for (int j = 0; j < 8; ++j) xv[0][j] = xop[j * 256];
#pragma unroll
  for (int j = 0; j < 8; ++j) xv[1][j] = xop[2048 + j * 256];
  float4 wrem = (float4){0.f, 0.f, 0.f, 0.f};
  if (tid < 32) wrem = xo4[(size_t)blockIdx.x * XO_PB + 8192 + tid];
  __builtin_amdgcn_sched_barrier(0);  // pin: xo issued before the pack loop

  // pack all A fragments while later batches stream in
  s16x8 af[9][2];   // [kk][tau], 72 VGPR
#pragma unroll
  for (int kk = 0; kk < 9; ++kk) {
    const int b = kk & 3;
    af[kk][0] = __builtin_bit_cast(s16x8, (u32x4){
        pack_bf(va[b][1].x, va[b][0].x), pack_bf(va[b][3].x, va[b][2].x),
        pack_bf(va[b][5].x, va[b][4].x), pack_bf(va[b][7].x, va[b][6].x)});
    af[kk][1] = __builtin_bit_cast(s16x8, (u32x4){
        pack_bf(va[b][1].y, va[b][0].y), pack_bf(va[b][3].y, va[b][2].y),
        pack_bf(va[b][5].y, va[b][4].y), pack_bf(va[b][7].y, va[b][6].y)});
    if (kk + 4 <= 8) LOADB(b, kk + 4)
  }
#undef LOADB

  __syncthreads();   // drains vmcnt (B half 0 + xo r0/r1 staged); all waves

  // ---- two action-half passes; argmax folds across h in registers ----
  float bv[2][4]; int bc[2][4];
#pragma unroll
  for (int h = 0; h < 2; ++h) {
    if (h == 1) {
      __syncthreads();             // everyone done reading half 0
      STAGE_BH(1)
      __syncthreads();             // half 1 staged (vmcnt drained here)
    }
    f32x4 acc[2][8];   // [tau][n]
#pragma unroll
    for (int tau = 0; tau < 2; ++tau)
#pragma unroll
      for (int n = 0; n < 8; ++n) acc[tau][n] = (f32x4){0.f, 0.f, 0.f, 0.f};
#pragma unroll
    for (int kk = 0; kk < 9; ++kk) {
      const unsigned char* bp = &Bh[(kk * 8 * 64 + lane) * 16];
#pragma unroll
      for (int n = 0; n < 8; ++n) {
        const s16x8 bfr = *(const s16x8*)(bp + n * 1024);
        acc[0][n] = __builtin_amdgcn_mfma_f32_16x16x32_bf16(
            af[kk][0], bfr, acc[0][n], 0, 0, 0);
        acc[1][n] = __builtin_amdgcn_mfma_f32_16x16x32_bf16(
            af[kk][1], bfr, acc[1][n], 0, 0, 0);
      }
    }
    // fold into running argmax: a = 128h + 16n + r16 (ascending => first-min)
#pragma unroll
    for (int n = 0; n < 8; ++n) {
      const int c = 128 * h + 16 * n + r16;
#pragma unroll
      for (int tau = 0; tau < 2; ++tau)
#pragma unroll
        for (int q = 0; q < 4; ++q) {
          const float v = acc[tau][n][q];
          if (h == 0 && n == 0) { bv[tau][q] = v; bc[tau][q] = c; }
          else if (v > bv[tau][q]) { bv[tau][q] = v; bc[tau][q] = c; }
        }
    }
  }
#undef STAGE_BH

  // cross-lane (r16) argmax; each lane's t = t0+32wv+2*(4g+q)+tau
#pragma unroll
  for (int m = 1; m <= 8; m <<= 1) {
#pragma unroll
    for (int tau = 0; tau < 2; ++tau)
#pragma unroll
      for (int q = 0; q < 4; ++q) {
        const float ov = __shfl_xor(bv[tau][q], m);
        const int   oc = __shfl_xor(bc[tau][q], m);
        if (ov > bv[tau][q] || (ov == bv[tau][q] && oc < bc[tau][q])) {
          bv[tau][q] = ov; bc[tau][q] = oc;
        }
      }
  }
  if (r16 == 0) {
#pragma unroll
    for (int tau = 0; tau < 2; ++tau)
#pragma unroll
      for (int q = 0; q < 4; ++q)
        atomicOr(&lmask[bc[tau][q] >> 5], 1u << (bc[tau][q] & 31));
  }
  __syncthreads();
  if (tid < 8) maskp[blockIdx.x * 8 + tid] = lmask[tid];

  // ---- xo main: consume round r (r0/r1 already resident), issue r+2 ----
  double ds = 0.0;
#pragma unroll
  for (int r = 0; r < 4; ++r) {
    float fs = 0.f;
#pragma unroll
    for (int j = 0; j < 8; ++j) {
      const float4 v = xv[r & 1][j];
      fs = fmaf(v.x, v.x, fs); fs = fmaf(v.y, v.y, fs);
      fs = fmaf(v.z, v.z, fs); fs = fmaf(v.w, v.w, fs);
    }
    ds += (double)fs;
    if (r + 2 < 4) {
#pragma unroll
      for (int j = 0; j < 8; ++j)
        xv[r & 1][j] = xop[(size_t)(r + 2) * 2048 + j * 256];
    }
  }
  {
    float fs = 0.f;
    fs = fmaf(wrem.x, wrem.x, fs); fs = fmaf(wrem.y, wrem.y, fs);
    fs = fmaf(wrem.z, wrem.z, fs); fs = fmaf(wrem.w, wrem.w, fs);
    ds += (double)fs;
  }
#pragma unroll
  for (int off = 32; off; off >>= 1) ds += __shfl_down(ds, off);
  if (lane == 0) sdw[wv] = ds;
  __syncthreads();
  if (tid == 0) partial[blockIdx.x] = sdw[0] + sdw[1] + sdw[2] + sdw[3];
}

// ---------------------------------------------------------------------------
// OR-reduce per-block masks (NBLK_G=512), then correction for columns t = a:
//   corrp[f] = sum_a sel[a] * ((G*xs)^2 - 2*(G*xs)*xo)
// ---------------------------------------------------------------------------
__global__ __launch_bounds__(256) void k_corr(
    const float* __restrict__ xs, const float* __restrict__ xo,
    const float* __restrict__ G, const unsigned* __restrict__ maskp,
    double* __restrict__ corrp) {
  __shared__ unsigned m8[8];
  const int tid = threadIdx.x;
  if (tid < 8) m8[tid] = 0u;
  __syncthreads();
  unsigned m = 0;
  for (int b = tid >> 3; b < NBLK_G; b += 32) m |= maskp[b * 8 + (tid & 7)];
  atomicOr(&m8[tid & 7], m);
  __syncthreads();
  const int f = blockIdx.x, a = tid;
  const bool sel = (m8[a >> 5] >> (a & 31)) & 1u;
  const float gv  = G[f * N_ACT + a];
  const float xsv = xs[(size_t)f * T_STEPS + a];
  const float xov = xo[(size_t)f * T_STEPS + a];
  const float gx  = gv * xsv;
  double acc = sel ? (double)(gx * (gx - 2.f * xov)) : 0.0;
#pragma unroll
  for (int off = 32; off; off >>= 1) acc += __shfl_down(acc, off);
  __shared__ double sdc[4];
  if ((tid & 63) == 0) sdc[tid >> 6] = acc;
  __syncthreads();
  if (tid == 0) corrp[f] = sdc[0] + sdc[1] + sdc[2] + sdc[3];
}

// ---------------------------------------------------------------------------
// Final reduction: partial[512] + corrp[257] -> loss
// ---------------------------------------------------------------------------
__global__ __launch_bounds__(256) void k_final(const double* __restrict__ partial,
                                               const double* __restrict__ corrp,
                                               float* __restrict__ out) {
  const int tid = threadIdx.x;
  double s = partial[tid] + partial[tid + 256] + corrp[tid];
  if (tid == 0) s += corrp[256];
#pragma unroll
  for (int off = 32; off; off >>= 1) s += __shfl_down(s, off);
  __shared__ double sd[4];
  if ((tid & 63) == 0) sd[tid >> 6] = s;
  __syncthreads();
  if (tid == 0)
    out[0] = (float)((sd[0] + sd[1] + sd[2] + sd[3]) /
                     ((double)F_BINS * (double)T_STEPS));
}

extern "C" void kernel_launch(void* const* d_in, const int* in_sizes, int n_in,
                              void* d_out, int out_size, void* d_ws, size_t ws_size,
                              hipStream_t stream) {
  const float* x_out    = (const float*)d_in[0];
  const float* x_source = (const float*)d_in[1];
  // d_in[2] (x_clean) is dead: argmin_a(clean_sum - proj) == argmax_a proj
  const float* G        = (const float*)d_in[3];

  char* ws = (char*)d_ws;
  double*        partial = (double*)(ws + WS_PART);
  double*        corrp   = (double*)(ws + WS_CORR);
  unsigned*      maskp   = (unsigned*)(ws + WS_MASK);
  unsigned char* gfrag   = (unsigned char*)(ws + WS_GFRAG);

  // no memset: partial, corrp, maskp, gfrag fully written every call
  k_prep <<<36, 256, 0, stream>>>(G, gfrag);
  k_gemm <<<NBLK_G, NTHR, 0, stream>>>(x_source, (const float4*)x_out,
                                       gfrag, maskp, partial);
  k_corr <<<F_BINS, 256, 0, stream>>>(x_source, x_out, G, maskp, corrp);
  k_final<<<1, 256, 0, stream>>>(partial, corrp, (float*)d_out);
}

// Round 24
// 40.504 us; speedup vs baseline: 1.4145x; 1.4145x over previous
//
#include <hip/hip_runtime.h>

#define F_BINS  257
#define T_STEPS 65536
#define N_ACT   256
#define TM      128           // t-columns per k_gemm block (4 waves x 32t)
#define NBLK_G  512           // T_STEPS / TM  -> 2 blocks/CU
#define NTHR    256           // 4 waves
#define XO_PB   8224          // float4 per block: 4210688/512 exact (32/thr + 32 rem)

typedef float f32x4 __attribute__((ext_vector_type(4)));
typedef short s16x8 __attribute__((ext_vector_type(8)));
typedef unsigned u32x4 __attribute__((ext_vector_type(4)));

// ws layout (all fully written every call - no memset needed):
//   [1024]   double partial[NBLK_G=512]  (per-block xo^2 sums)
//   [20480]  double corrp[257]           (per-f correction sums)
//   [24576]  unsigned maskp[NBLK_G*8]
//   [65536]  uchar Gfrag[147456]         (B frags: [kk][ng][lane][16B])
#define WS_PART  1024
#define WS_CORR  20480
#define WS_MASK  24576
#define WS_GFRAG 65536

__device__ __forceinline__ unsigned short f2bf_rne(float x) {
  unsigned u = __builtin_bit_cast(unsigned, x);
  return (unsigned short)((u + 0x7FFFu + ((u >> 16) & 1u)) >> 16);
}
// bf16(hi)<<16 | bf16(lo) by truncation: one v_perm_b32
__device__ __forceinline__ unsigned pack_bf(float hi, float lo) {
  return __builtin_amdgcn_perm(__builtin_bit_cast(unsigned, hi),
                               __builtin_bit_cast(unsigned, lo), 0x07060302u);
}

// ---------------------------------------------------------------------------
// B fragments in MFMA order:
// Gfrag[((kk*16+ng)*64+lane)*16] = 8 bf16 of G[f=32kk+8(lane>>4)+j][a=16ng+(lane&15)]
// ---------------------------------------------------------------------------
__global__ __launch_bounds__(256) void k_prep(const float* __restrict__ G,
                                              unsigned char* __restrict__ gfrag) {
  const int u = blockIdx.x * 256 + threadIdx.x;   // 0..9215
  const int lane = u & 63, ng = (u >> 6) & 15, kk = u >> 10;
  const int r16 = lane & 15, g = lane >> 4;
  const int a = ng * 16 + r16;
  unsigned short h[8];
#pragma unroll
  for (int j = 0; j < 8; ++j) {
    const int f = kk * 32 + 8 * g + j;
    h[j] = (f < F_BINS) ? f2bf_rne(G[f * N_ACT + a]) : (unsigned short)0;
  }
  u32x4 w;
#pragma unroll
  for (int i = 0; i < 4; ++i)
    w[i] = (unsigned)h[2 * i] | ((unsigned)h[2 * i + 1] << 16);
  *(u32x4*)(gfrag + (size_t)u * 16) = w;
}

// ---------------------------------------------------------------------------
// GEMM+argmax+xo^2, 2 blocks/CU (R18 core + R22's 2-deep post-loop xo
// prefill). Verified best configuration (R22: 40.8us). The xo prefill must
// stay AFTER the K-loop: placing it in the prologue (R23) spills xv to
// scratch because va+af+xv cannot coexist in the 128-VGPR budget.
// ---------------------------------------------------------------------------
__global__ __launch_bounds__(NTHR, 2) void k_gemm(
    const float* __restrict__ xs, const float4* __restrict__ xo4,
    const unsigned char* __restrict__ gfrag,
    unsigned* __restrict__ maskp, double* __restrict__ partial) {
  const int tid = threadIdx.x, lane = tid & 63, wv = tid >> 6;
  const int g = lane >> 4, r16 = lane & 15;
  const int t0 = blockIdx.x * TM;
  const int tcol = t0 + 32 * wv + 2 * r16;   // float2 load column

  __shared__ __align__(16) unsigned char Bh[73728];  // one action-half of B
  __shared__ unsigned lmask[8];
  __shared__ double sdw[4];
  if (tid < 8) lmask[tid] = 0u;

  // stage action-half hv: 72 chunks of 1KB; wave wv does idx 18wv..18wv+17
#define STAGE_BH(hv)                                                          \
  {                                                                           \
    _Pragma("unroll") for (int idx = 0; idx < 18; ++idx) {                    \
      const int j = 18 * wv + idx;         /* 0..71: dst chunk */             \
      const int kkc = j >> 3, ic = j & 7;                                     \
      const unsigned char* src = gfrag +                                      \
          (size_t)(kkc * 16 + 8 * (hv) + ic) * 1024 + (size_t)lane * 16;      \
      unsigned char* dst = &Bh[j * 1024];                                     \
      __builtin_amdgcn_global_load_lds(                                       \
          (const __attribute__((address_space(1))) unsigned*)src,             \
          (__attribute__((address_space(3))) unsigned*)dst, 16, 0, 0);        \
    }                                                                         \
  }
  // A batch: 8 float2 loads (f-rows 32kkv+8g..+8g+7 at fixed 2 t's)
#define LOADB(slot, kkv)                                                      \
  {                                                                           \
    _Pragma("unroll") for (int j = 0; j < 8; ++j) {                           \
      int f = 32 * (kkv) + 8 * g + j;                                         \
      if ((kkv) == 8) f = f > 256 ? 256 : f; /* Gfrag zero rows cover pad */  \
      va[slot][j] = *(const float2*)(xs + (size_t)f * T_STEPS + tcol);        \
    }                                                                         \
  }

  float2 va[4][8];
  LOADB(0, 0) LOADB(1, 1) LOADB(2, 2) LOADB(3, 3)
  __builtin_amdgcn_sched_barrier(0);
  STAGE_BH(0)                      // after A batches 0-3, before 4-8
  __builtin_amdgcn_sched_barrier(0);

  // pack all A fragments while later batches stream in
  s16x8 af[9][2];   // [kk][tau], 72 VGPR
#pragma unroll
  for (int kk = 0; kk < 9; ++kk) {
    const int b = kk & 3;
    af[kk][0] = __builtin_bit_cast(s16x8, (u32x4){
        pack_bf(va[b][1].x, va[b][0].x), pack_bf(va[b][3].x, va[b][2].x),
        pack_bf(va[b][5].x, va[b][4].x), pack_bf(va[b][7].x, va[b][6].x)});
    af[kk][1] = __builtin_bit_cast(s16x8, (u32x4){
        pack_bf(va[b][1].y, va[b][0].y), pack_bf(va[b][3].y, va[b][2].y),
        pack_bf(va[b][5].y, va[b][4].y), pack_bf(va[b][7].y, va[b][6].y)});
    if (kk + 4 <= 8) LOADB(b, kk + 4)
  }
#undef LOADB

  __syncthreads();   // drains vmcnt (B half 0 staged) + all waves arrived

  // ---- two action-half passes; argmax folds across h in registers ----
  float bv[2][4]; int bc[2][4];
#pragma unroll
  for (int h = 0; h < 2; ++h) {
    if (h == 1) {
      __syncthreads();             // everyone done reading half 0
      STAGE_BH(1)
      __syncthreads();             // half 1 staged (vmcnt drained here)
    }
    f32x4 acc[2][8];   // [tau][n]
#pragma unroll
    for (int tau = 0; tau < 2; ++tau)
#pragma unroll
      for (int n = 0; n < 8; ++n) acc[tau][n] = (f32x4){0.f, 0.f, 0.f, 0.f};
#pragma unroll
    for (int kk = 0; kk < 9; ++kk) {
      const unsigned char* bp = &Bh[(kk * 8 * 64 + lane) * 16];
#pragma unroll
      for (int n = 0; n < 8; ++n) {
        const s16x8 bfr = *(const s16x8*)(bp + n * 1024);
        acc[0][n] = __builtin_amdgcn_mfma_f32_16x16x32_bf16(
            af[kk][0], bfr, acc[0][n], 0, 0, 0);
        acc[1][n] = __builtin_amdgcn_mfma_f32_16x16x32_bf16(
            af[kk][1], bfr, acc[1][n], 0, 0, 0);
      }
    }
    // fold into running argmax: a = 128h + 16n + r16 (ascending => first-min)
#pragma unroll
    for (int n = 0; n < 8; ++n) {
      const int c = 128 * h + 16 * n + r16;
#pragma unroll
      for (int tau = 0; tau < 2; ++tau)
#pragma unroll
        for (int q = 0; q < 4; ++q) {
          const float v = acc[tau][n][q];
          if (h == 0 && n == 0) { bv[tau][q] = v; bc[tau][q] = c; }
          else if (v > bv[tau][q]) { bv[tau][q] = v; bc[tau][q] = c; }
        }
    }
  }
#undef STAGE_BH

  // ---- issue xo rounds 0 AND 1 (+remainder) early: post-barrier region,
  //      argmax shuffles + lmask writeback hide the ramp (2 rounds deep) ----
  const float4* xop = xo4 + (size_t)blockIdx.x * XO_PB + tid;
  float4 xv[2][8];
#pragma unroll
  for (int j = 0; j < 8; ++j) xv[0][j] = xop[j * 256];
#pragma unroll
  for (int j = 0; j < 8; ++j) xv[1][j] = xop[2048 + j * 256];
  float4 wrem = (float4){0.f, 0.f, 0.f, 0.f};
  if (tid < 32) wrem = xo4[(size_t)blockIdx.x * XO_PB + 8192 + tid];

  // cross-lane (r16) argmax; each lane's t = t0+32wv+2*(4g+q)+tau
#pragma unroll
  for (int m = 1; m <= 8; m <<= 1) {
#pragma unroll
    for (int tau = 0; tau < 2; ++tau)
#pragma unroll
      for (int q = 0; q < 4; ++q) {
        const float ov = __shfl_xor(bv[tau][q], m);
        const int   oc = __shfl_xor(bc[tau][q], m);
        if (ov > bv[tau][q] || (ov == bv[tau][q] && oc < bc[tau][q])) {
          bv[tau][q] = ov; bc[tau][q] = oc;
        }
      }
  }
  if (r16 == 0) {
#pragma unroll
    for (int tau = 0; tau < 2; ++tau)
#pragma unroll
      for (int q = 0; q < 4; ++q)
        atomicOr(&lmask[bc[tau][q] >> 5], 1u << (bc[tau][q] & 31));
  }
  __syncthreads();
  if (tid < 8) maskp[blockIdx.x * 8 + tid] = lmask[tid];

  // ---- xo main: consume round r, then issue round r+2 into slot r&1 ----
  double ds = 0.0;
#pragma unroll
  for (int r = 0; r < 4; ++r) {
    float fs = 0.f;
#pragma unroll
    for (int j = 0; j < 8; ++j) {
      const float4 v = xv[r & 1][j];
      fs = fmaf(v.x, v.x, fs); fs = fmaf(v.y, v.y, fs);
      fs = fmaf(v.z, v.z, fs); fs = fmaf(v.w, v.w, fs);
    }
    ds += (double)fs;
    if (r + 2 < 4) {
#pragma unroll
      for (int j = 0; j < 8; ++j)
        xv[r & 1][j] = xop[(size_t)(r + 2) * 2048 + j * 256];
    }
  }
  {
    float fs = 0.f;
    fs = fmaf(wrem.x, wrem.x, fs); fs = fmaf(wrem.y, wrem.y, fs);
    fs = fmaf(wrem.z, wrem.z, fs); fs = fmaf(wrem.w, wrem.w, fs);
    ds += (double)fs;
  }
#pragma unroll
  for (int off = 32; off; off >>= 1) ds += __shfl_down(ds, off);
  if (lane == 0) sdw[wv] = ds;
  __syncthreads();
  if (tid == 0) partial[blockIdx.x] = sdw[0] + sdw[1] + sdw[2] + sdw[3];
}

// ---------------------------------------------------------------------------
// OR-reduce per-block masks (NBLK_G=512), then correction for columns t = a:
//   corrp[f] = sum_a sel[a] * ((G*xs)^2 - 2*(G*xs)*xo)
// ---------------------------------------------------------------------------
__global__ __launch_bounds__(256) void k_corr(
    const float* __restrict__ xs, const float* __restrict__ xo,
    const float* __restrict__ G, const unsigned* __restrict__ maskp,
    double* __restrict__ corrp) {
  __shared__ unsigned m8[8];
  const int tid = threadIdx.x;
  if (tid < 8) m8[tid] = 0u;
  __syncthreads();
  unsigned m = 0;
  for (int b = tid >> 3; b < NBLK_G; b += 32) m |= maskp[b * 8 + (tid & 7)];
  atomicOr(&m8[tid & 7], m);
  __syncthreads();
  const int f = blockIdx.x, a = tid;
  const bool sel = (m8[a >> 5] >> (a & 31)) & 1u;
  const float gv  = G[f * N_ACT + a];
  const float xsv = xs[(size_t)f * T_STEPS + a];
  const float xov = xo[(size_t)f * T_STEPS + a];
  const float gx  = gv * xsv;
  double acc = sel ? (double)(gx * (gx - 2.f * xov)) : 0.0;
#pragma unroll
  for (int off = 32; off; off >>= 1) acc += __shfl_down(acc, off);
  __shared__ double sdc[4];
  if ((tid & 63) == 0) sdc[tid >> 6] = acc;
  __syncthreads();
  if (tid == 0) corrp[f] = sdc[0] + sdc[1] + sdc[2] + sdc[3];
}

// ---------------------------------------------------------------------------
// Final reduction: partial[512] + corrp[257] -> loss
// ---------------------------------------------------------------------------
__global__ __launch_bounds__(256) void k_final(const double* __restrict__ partial,
                                               const double* __restrict__ corrp,
                                               float* __restrict__ out) {
  const int tid = threadIdx.x;
  double s = partial[tid] + partial[tid + 256] + corrp[tid];
  if (tid == 0) s += corrp[256];
#pragma unroll
  for (int off = 32; off; off >>= 1) s += __shfl_down(s, off);
  __shared__ double sd[4];
  if ((tid & 63) == 0) sd[tid >> 6] = s;
  __syncthreads();
  if (tid == 0)
    out[0] = (float)((sd[0] + sd[1] + sd[2] + sd[3]) /
                     ((double)F_BINS * (double)T_STEPS));
}

extern "C" void kernel_launch(void* const* d_in, const int* in_sizes, int n_in,
                              void* d_out, int out_size, void* d_ws, size_t ws_size,
                              hipStream_t stream) {
  const float* x_out    = (const float*)d_in[0];
  const float* x_source = (const float*)d_in[1];
  // d_in[2] (x_clean) is dead: argmin_a(clean_sum - proj) == argmax_a proj
  const float* G        = (const float*)d_in[3];

  char* ws = (char*)d_ws;
  double*        partial = (double*)(ws + WS_PART);
  double*        corrp   = (double*)(ws + WS_CORR);
  unsigned*      maskp   = (unsigned*)(ws + WS_MASK);
  unsigned char* gfrag   = (unsigned char*)(ws + WS_GFRAG);

  // no memset: partial, corrp, maskp, gfrag fully written every call
  k_prep <<<36, 256, 0, stream>>>(G, gfrag);
  k_gemm <<<NBLK_G, NTHR, 0, stream>>>(x_source, (const float4*)x_out,
                                       gfrag, maskp, partial);
  k_corr <<<F_BINS, 256, 0, stream>>>(x_source, x_out, G, maskp, corrp);
  k_final<<<1, 256, 0, stream>>>(partial, corrp, (float*)d_out);
}

// Round 25
// 40.482 us; speedup vs baseline: 1.4153x; 1.0006x over previous
//
#include <hip/hip_runtime.h>

#define F_BINS  257
#define T_STEPS 65536
#define N_ACT   256
#define TM      128           // t-columns per k_gemm block (4 waves x 32t)
#define NBLK_G  512           // T_STEPS / TM  -> 2 blocks/CU
#define NTHR    256           // 4 waves
#define XO_PB   8224          // float4 per block: 4210688/512 exact (32/thr + 32 rem)
#define PREP_BLKS 36
#define CORR_BLKS 16          // 16 blocks x 17 f-rows cover f=0..256

typedef float f32x4 __attribute__((ext_vector_type(4)));
typedef short s16x8 __attribute__((ext_vector_type(8)));
typedef unsigned u32x4 __attribute__((ext_vector_type(4)));

// ws layout (all fully written every call - no memset needed):
//   [1024]   double partial[NBLK_G=512]   (per-block xo^2 sums)
//   [8192]   double cpart[CORR_BLKS*256]  (mask-free per-action corr partials)
//   [40960]  unsigned maskp[NBLK_G*8]
//   [65536]  uchar Gfrag[147456]          (B frags: [kk][ng][lane][16B])
#define WS_PART  1024
#define WS_CPART 8192
#define WS_MASK  40960
#define WS_GFRAG 65536

__device__ __forceinline__ unsigned short f2bf_rne(float x) {
  unsigned u = __builtin_bit_cast(unsigned, x);
  return (unsigned short)((u + 0x7FFFu + ((u >> 16) & 1u)) >> 16);
}
// bf16(hi)<<16 | bf16(lo) by truncation: one v_perm_b32
__device__ __forceinline__ unsigned pack_bf(float hi, float lo) {
  return __builtin_amdgcn_perm(__builtin_bit_cast(unsigned, hi),
                               __builtin_bit_cast(unsigned, lo), 0x07060302u);
}

// ---------------------------------------------------------------------------
// Fused prep + mask-free correction partials (both independent of k_gemm):
// blocks 0..35: Gfrag build. Blocks 36..51: cpart[b][a] = sum over this
// block's f-rows of (G*xs)^2 - 2*(G*xs)*xo at column t=a. The mask only
// WEIGHTS these sums, so they can run before the GEMM; k_final applies sel.
// ---------------------------------------------------------------------------
__global__ __launch_bounds__(256) void k_pre(
    const float* __restrict__ G, const float* __restrict__ xs,
    const float* __restrict__ xo, unsigned char* __restrict__ gfrag,
    double* __restrict__ cpart) {
  const int tid = threadIdx.x;
  if (blockIdx.x < PREP_BLKS) {
    // Gfrag[((kk*16+ng)*64+lane)*16] = 8 bf16 of
    //   G[f=32kk+8(lane>>4)+j][a=16ng+(lane&15)], zero for f>=257
    const int u = blockIdx.x * 256 + tid;   // 0..9215
    const int lane = u & 63, ng = (u >> 6) & 15, kk = u >> 10;
    const int r16 = lane & 15, g = lane >> 4;
    const int a = ng * 16 + r16;
    unsigned short h[8];
#pragma unroll
    for (int j = 0; j < 8; ++j) {
      const int f = kk * 32 + 8 * g + j;
      h[j] = (f < F_BINS) ? f2bf_rne(G[f * N_ACT + a]) : (unsigned short)0;
    }
    u32x4 w;
#pragma unroll
    for (int i = 0; i < 4; ++i)
      w[i] = (unsigned)h[2 * i] | ((unsigned)h[2 * i + 1] << 16);
    *(u32x4*)(gfrag + (size_t)u * 16) = w;
    return;
  }
  // ---- mask-free correction partials ----
  const int b = blockIdx.x - PREP_BLKS;   // 0..15
  const int a = tid;
  const int f0 = b * 17;
  const int f1 = f0 + 17 > F_BINS ? F_BINS : f0 + 17;
  double ca = 0.0;
  for (int f = f0; f < f1; ++f) {
    const float gv  = G[f * N_ACT + a];
    const float xsv = xs[(size_t)f * T_STEPS + a];
    const float xov = xo[(size_t)f * T_STEPS + a];
    const float gx  = gv * xsv;
    ca += (double)(gx * (gx - 2.f * xov));
  }
  cpart[b * 256 + a] = ca;
}

// ---------------------------------------------------------------------------
// GEMM+argmax+xo^2, 2 blocks/CU — byte-identical to R22/R24 (40.5us best).
// xo prefill must stay AFTER the K-loop (R23: prologue placement spills).
// ---------------------------------------------------------------------------
__global__ __launch_bounds__(NTHR, 2) void k_gemm(
    const float* __restrict__ xs, const float4* __restrict__ xo4,
    const unsigned char* __restrict__ gfrag,
    unsigned* __restrict__ maskp, double* __restrict__ partial) {
  const int tid = threadIdx.x, lane = tid & 63, wv = tid >> 6;
  const int g = lane >> 4, r16 = lane & 15;
  const int t0 = blockIdx.x * TM;
  const int tcol = t0 + 32 * wv + 2 * r16;   // float2 load column

  __shared__ __align__(16) unsigned char Bh[73728];  // one action-half of B
  __shared__ unsigned lmask[8];
  __shared__ double sdw[4];
  if (tid < 8) lmask[tid] = 0u;

  // stage action-half hv: 72 chunks of 1KB; wave wv does idx 18wv..18wv+17
#define STAGE_BH(hv)                                                          \
  {                                                                           \
    _Pragma("unroll") for (int idx = 0; idx < 18; ++idx) {                    \
      const int j = 18 * wv + idx;         /* 0..71: dst chunk */             \
      const int kkc = j >> 3, ic = j & 7;                                     \
      const unsigned char* src = gfrag +                                      \
          (size_t)(kkc * 16 + 8 * (hv) + ic) * 1024 + (size_t)lane * 16;      \
      unsigned char* dst = &Bh[j * 1024];                                     \
      __builtin_amdgcn_global_load_lds(                                       \
          (const __attribute__((address_space(1))) unsigned*)src,             \
          (__attribute__((address_space(3))) unsigned*)dst, 16, 0, 0);        \
    }                                                                         \
  }
  // A batch: 8 float2 loads (f-rows 32kkv+8g..+8g+7 at fixed 2 t's)
#define LOADB(slot, kkv)                                                      \
  {                                                                           \
    _Pragma("unroll") for (int j = 0; j < 8; ++j) {                           \
      int f = 32 * (kkv) + 8 * g + j;                                         \
      if ((kkv) == 8) f = f > 256 ? 256 : f; /* Gfrag zero rows cover pad */  \
      va[slot][j] = *(const float2*)(xs + (size_t)f * T_STEPS + tcol);        \
    }                                                                         \
  }

  float2 va[4][8];
  LOADB(0, 0) LOADB(1, 1) LOADB(2, 2) LOADB(3, 3)
  __builtin_amdgcn_sched_barrier(0);
  STAGE_BH(0)                      // after A batches 0-3, before 4-8
  __builtin_amdgcn_sched_barrier(0);

  // pack all A fragments while later batches stream in
  s16x8 af[9][2];   // [kk][tau], 72 VGPR
#pragma unroll
  for (int kk = 0; kk < 9; ++kk) {
    const int b = kk & 3;
    af[kk][0] = __builtin_bit_cast(s16x8, (u32x4){
        pack_bf(va[b][1].x, va[b][0].x), pack_bf(va[b][3].x, va[b][2].x),
        pack_bf(va[b][5].x, va[b][4].x), pack_bf(va[b][7].x, va[b][6].x)});
    af[kk][1] = __builtin_bit_cast(s16x8, (u32x4){
        pack_bf(va[b][1].y, va[b][0].y), pack_bf(va[b][3].y, va[b][2].y),
        pack_bf(va[b][5].y, va[b][4].y), pack_bf(va[b][7].y, va[b][6].y)});
    if (kk + 4 <= 8) LOADB(b, kk + 4)
  }
#undef LOADB

  __syncthreads();   // drains vmcnt (B half 0 staged) + all waves arrived

  // ---- two action-half passes; argmax folds across h in registers ----
  float bv[2][4]; int bc[2][4];
#pragma unroll
  for (int h = 0; h < 2; ++h) {
    if (h == 1) {
      __syncthreads();             // everyone done reading half 0
      STAGE_BH(1)
      __syncthreads();             // half 1 staged (vmcnt drained here)
    }
    f32x4 acc[2][8];   // [tau][n]
#pragma unroll
    for (int tau = 0; tau < 2; ++tau)
#pragma unroll
      for (int n = 0; n < 8; ++n) acc[tau][n] = (f32x4){0.f, 0.f, 0.f, 0.f};
#pragma unroll
    for (int kk = 0; kk < 9; ++kk) {
      const unsigned char* bp = &Bh[(kk * 8 * 64 + lane) * 16];
#pragma unroll
      for (int n = 0; n < 8; ++n) {
        const s16x8 bfr = *(const s16x8*)(bp + n * 1024);
        acc[0][n] = __builtin_amdgcn_mfma_f32_16x16x32_bf16(
            af[kk][0], bfr, acc[0][n], 0, 0, 0);
        acc[1][n] = __builtin_amdgcn_mfma_f32_16x16x32_bf16(
            af[kk][1], bfr, acc[1][n], 0, 0, 0);
      }
    }
    // fold into running argmax: a = 128h + 16n + r16 (ascending => first-min)
#pragma unroll
    for (int n = 0; n < 8; ++n) {
      const int c = 128 * h + 16 * n + r16;
#pragma unroll
      for (int tau = 0; tau < 2; ++tau)
#pragma unroll
        for (int q = 0; q < 4; ++q) {
          const float v = acc[tau][n][q];
          if (h == 0 && n == 0) { bv[tau][q] = v; bc[tau][q] = c; }
          else if (v > bv[tau][q]) { bv[tau][q] = v; bc[tau][q] = c; }
        }
    }
  }
#undef STAGE_BH

  // ---- issue xo rounds 0 AND 1 (+remainder) early: post-barrier region,
  //      argmax shuffles + lmask writeback hide the ramp (2 rounds deep) ----
  const float4* xop = xo4 + (size_t)blockIdx.x * XO_PB + tid;
  float4 xv[2][8];
#pragma unroll
  for (int j = 0; j < 8; ++j) xv[0][j] = xop[j * 256];
#pragma unroll
  for (int j = 0; j < 8; ++j) xv[1][j] = xop[2048 + j * 256];
  float4 wrem = (float4){0.f, 0.f, 0.f, 0.f};
  if (tid < 32) wrem = xo4[(size_t)blockIdx.x * XO_PB + 8192 + tid];

  // cross-lane (r16) argmax; each lane's t = t0+32wv+2*(4g+q)+tau
#pragma unroll
  for (int m = 1; m <= 8; m <<= 1) {
#pragma unroll
    for (int tau = 0; tau < 2; ++tau)
#pragma unroll
      for (int q = 0; q < 4; ++q) {
        const float ov = __shfl_xor(bv[tau][q], m);
        const int   oc = __shfl_xor(bc[tau][q], m);
        if (ov > bv[tau][q] || (ov == bv[tau][q] && oc < bc[tau][q])) {
          bv[tau][q] = ov; bc[tau][q] = oc;
        }
      }
  }
  if (r16 == 0) {
#pragma unroll
    for (int tau = 0; tau < 2; ++tau)
#pragma unroll
      for (int q = 0; q < 4; ++q)
        atomicOr(&lmask[bc[tau][q] >> 5], 1u << (bc[tau][q] & 31));
  }
  __syncthreads();
  if (tid < 8) maskp[blockIdx.x * 8 + tid] = lmask[tid];

  // ---- xo main: consume round r, then issue round r+2 into slot r&1 ----
  double ds = 0.0;
#pragma unroll
  for (int r = 0; r < 4; ++r) {
    float fs = 0.f;
#pragma unroll
    for (int j = 0; j < 8; ++j) {
      const float4 v = xv[r & 1][j];
      fs = fmaf(v.x, v.x, fs); fs = fmaf(v.y, v.y, fs);
      fs = fmaf(v.z, v.z, fs); fs = fmaf(v.w, v.w, fs);
    }
    ds += (double)fs;
    if (r + 2 < 4) {
#pragma unroll
      for (int j = 0; j < 8; ++j)
        xv[r & 1][j] = xop[(size_t)(r + 2) * 2048 + j * 256];
    }
  }
  {
    float fs = 0.f;
    fs = fmaf(wrem.x, wrem.x, fs); fs = fmaf(wrem.y, wrem.y, fs);
    fs = fmaf(wrem.z, wrem.z, fs); fs = fmaf(wrem.w, wrem.w, fs);
    ds += (double)fs;
  }
#pragma unroll
  for (int off = 32; off; off >>= 1) ds += __shfl_down(ds, off);
  if (lane == 0) sdw[wv] = ds;
  __syncthreads();
  if (tid == 0) partial[blockIdx.x] = sdw[0] + sdw[1] + sdw[2] + sdw[3];
}

// ---------------------------------------------------------------------------
// Final: OR-reduce per-block masks, apply sel-weighting to the precomputed
// cpart sums, add xo^2 partials, write the loss. One 256-thread block.
// ---------------------------------------------------------------------------
__global__ __launch_bounds__(256) void k_final(
    const double* __restrict__ partial, const double* __restrict__ cpart,
    const unsigned* __restrict__ maskp, float* __restrict__ out) {
  __shared__ unsigned m8[8];
  const int tid = threadIdx.x;
  if (tid < 8) m8[tid] = 0u;
  __syncthreads();
  unsigned m = 0;
  for (int b = tid >> 3; b < NBLK_G; b += 32) m |= maskp[b * 8 + (tid & 7)];
  atomicOr(&m8[tid & 7], m);
  __syncthreads();
  const int a = tid;   // action id = selected column t
  const bool sel = (m8[a >> 5] >> (a & 31)) & 1u;
  double c = 0.0;
#pragma unroll
  for (int i = 0; i < CORR_BLKS; ++i) c += cpart[i * 256 + a];
  double s = partial[tid] + partial[tid + 256] + (sel ? c : 0.0);
#pragma unroll
  for (int off = 32; off; off >>= 1) s += __shfl_down(s, off);
  __shared__ double sd[4];
  if ((tid & 63) == 0) sd[tid >> 6] = s;
  __syncthreads();
  if (tid == 0)
    out[0] = (float)((sd[0] + sd[1] + sd[2] + sd[3]) /
                     ((double)F_BINS * (double)T_STEPS));
}

extern "C" void kernel_launch(void* const* d_in, const int* in_sizes, int n_in,
                              void* d_out, int out_size, void* d_ws, size_t ws_size,
                              hipStream_t stream) {
  const float* x_out    = (const float*)d_in[0];
  const float* x_source = (const float*)d_in[1];
  // d_in[2] (x_clean) is dead: argmin_a(clean_sum - proj) == argmax_a proj
  const float* G        = (const float*)d_in[3];

  char* ws = (char*)d_ws;
  double*        partial = (double*)(ws + WS_PART);
  double*        cpart   = (double*)(ws + WS_CPART);
  unsigned*      maskp   = (unsigned*)(ws + WS_MASK);
  unsigned char* gfrag   = (unsigned char*)(ws + WS_GFRAG);

  // no memset: partial, cpart, maskp, gfrag fully written every call
  k_pre  <<<PREP_BLKS + CORR_BLKS, 256, 0, stream>>>(G, x_source, x_out,
                                                     gfrag, cpart);
  k_gemm <<<NBLK_G, NTHR, 0, stream>>>(x_source, (const float4*)x_out,
                                       gfrag, maskp, partial);
  k_final<<<1, 256, 0, stream>>>(partial, cpart, maskp, (float*)d_out);
}